// Round 1
// baseline (3075.496 us; speedup 1.0000x reference)
//
#include <hip/hip_runtime.h>

// Problem: N=1e6 nodes, E=32e6 edges.
// out[i] = (sum_{e: dst=i} h2[src_e]) / max(deg_in(i),1) * Wsage
// h2[v] = sum_j W2[j]*relu(W1[j]*x[v]+b1[j]) + b2
//
// ws layout (floats): [0,N) agg, [N,2N) cnt, then 1 int flag (edge dtype).
// d_out is reused as the h2 buffer (overwritten by out_kernel at the end).

// ---- dtype probe: int64 edge_index => every odd 32-bit word is 0 ----
__global__ void detect_dtype_kernel(const int* __restrict__ ei, int* __restrict__ flag) {
    if (threadIdx.x == 0 && blockIdx.x == 0) {
        int is64 = 1;
        for (int i = 1; i < 256; i += 2) {
            if (ei[i] != 0) { is64 = 0; break; }
        }
        *flag = is64;
    }
}

__global__ void node_kernel(const float* __restrict__ x,
                            const float* __restrict__ W1,
                            const float* __restrict__ b1,
                            const float* __restrict__ W2,
                            const float* __restrict__ b2,
                            float* __restrict__ h2,
                            float* __restrict__ agg,
                            float* __restrict__ cnt,
                            int n) {
    int i = blockIdx.x * blockDim.x + threadIdx.x;
    if (i >= n) return;
    float xi = x[i];
    float acc = b2[0];
#pragma unroll
    for (int j = 0; j < 4; ++j) {
        float t = fmaxf(W1[j] * xi + b1[j], 0.0f);
        acc += W2[j] * t;
    }
    h2[i]  = acc;
    agg[i] = 0.0f;
    cnt[i] = 0.0f;
}

__global__ void edge_kernel(const int* __restrict__ ei,
                            const float* __restrict__ h2,
                            float* __restrict__ agg,
                            float* __restrict__ cnt,
                            const int* __restrict__ flag,
                            long long E) {
    long long i      = (long long)blockIdx.x * blockDim.x + threadIdx.x;
    long long stride = (long long)gridDim.x * blockDim.x;
    const int is64 = *flag;  // uniform, L2-cached broadcast
    if (is64) {
        const long long* e64 = (const long long*)ei;
        for (long long e = i; e < E; e += stride) {
            int s = (int)e64[e];
            int d = (int)e64[E + e];
            atomicAdd(&agg[d], h2[s]);
            atomicAdd(&cnt[d], 1.0f);
        }
    } else {
        for (long long e = i; e < E; e += stride) {
            int s = ei[e];
            int d = ei[E + e];
            atomicAdd(&agg[d], h2[s]);
            atomicAdd(&cnt[d], 1.0f);
        }
    }
}

__global__ void out_kernel(const float* __restrict__ agg,
                           const float* __restrict__ cnt,
                           const float* __restrict__ Wsage,
                           float* __restrict__ out,
                           int n) {
    int i = blockIdx.x * blockDim.x + threadIdx.x;
    if (i >= n) return;
    out[i] = agg[i] / fmaxf(cnt[i], 1.0f) * Wsage[0];
}

extern "C" void kernel_launch(void* const* d_in, const int* in_sizes, int n_in,
                              void* d_out, int out_size, void* d_ws, size_t ws_size,
                              hipStream_t stream) {
    const float* x     = (const float*)d_in[0];
    const int*   ei    = (const int*)d_in[1];
    const float* W1    = (const float*)d_in[2];
    const float* b1    = (const float*)d_in[3];
    const float* W2    = (const float*)d_in[4];
    const float* b2    = (const float*)d_in[5];
    const float* Wsage = (const float*)d_in[6];

    const int       n = in_sizes[0];            // 1,000,000
    const long long E = (long long)in_sizes[1] / 2;  // 32,000,000

    float* agg  = (float*)d_ws;
    float* cnt  = agg + n;
    int*   flag = (int*)(cnt + n);
    float* h2   = (float*)d_out;  // reuse output buffer as h2 scratch

    detect_dtype_kernel<<<1, 64, 0, stream>>>(ei, flag);

    {
        int threads = 256;
        int blocks  = (n + threads - 1) / threads;
        node_kernel<<<blocks, threads, 0, stream>>>(x, W1, b1, W2, b2, h2, agg, cnt, n);
    }
    {
        int threads = 256;
        int blocks  = 2048;  // grid-stride, ~61 iters/thread
        edge_kernel<<<blocks, threads, 0, stream>>>(ei, h2, agg, cnt, flag, E);
    }
    {
        int threads = 256;
        int blocks  = (n + threads - 1) / threads;
        out_kernel<<<blocks, threads, 0, stream>>>(agg, cnt, Wsage, (float*)d_out, n);
    }
}

// Round 2
// 1387.312 us; speedup vs baseline: 2.2169x; 2.2169x over previous
//
#include <hip/hip_runtime.h>

// Problem: N=1e6 nodes, E=32e6 edges.
// out[i] = (sum_{e: dst=i} h2[src_e]) / max(deg_in(i),1) * Wsage
// h2[v] = sum_j W2[j]*relu(W1[j]*x[v]+b1[j]) + b2
//
// Key optimization (R1): pack (agg, cnt) into ONE f64 atomic per edge.
//   val = h2[src] + 2^20   accumulated into packed[dst] (f64 atomic add)
//   decode: cnt = round(val/2^20); agg = val - cnt*2^20
// Safe because |agg| < 2^19 and cnt*2^20 < 2^30 (53-bit mantissa; ulp ~6e-8).
//
// ws layout: [0, 8N) bytes = packed (double[N]); then 1 int flag (edge dtype).
// d_out is reused as the h2 buffer (overwritten by out_kernel at the end).

#define PACK_SCALE 1048576.0  // 2^20

// ---- dtype probe: int64 edge_index => every odd 32-bit word is 0 ----
__global__ void detect_dtype_kernel(const int* __restrict__ ei, int* __restrict__ flag) {
    if (threadIdx.x == 0 && blockIdx.x == 0) {
        int is64 = 1;
        for (int i = 1; i < 256; i += 2) {
            if (ei[i] != 0) { is64 = 0; break; }
        }
        *flag = is64;
    }
}

__global__ void node_kernel(const float* __restrict__ x,
                            const float* __restrict__ W1,
                            const float* __restrict__ b1,
                            const float* __restrict__ W2,
                            const float* __restrict__ b2,
                            float* __restrict__ h2,
                            double* __restrict__ packed,
                            int n) {
    int i = blockIdx.x * blockDim.x + threadIdx.x;
    if (i >= n) return;
    float xi = x[i];
    float acc = b2[0];
#pragma unroll
    for (int j = 0; j < 4; ++j) {
        float t = fmaxf(W1[j] * xi + b1[j], 0.0f);
        acc += W2[j] * t;
    }
    h2[i]     = acc;
    packed[i] = 0.0;
}

__global__ void edge_kernel(const int* __restrict__ ei,
                            const float* __restrict__ h2,
                            double* __restrict__ packed,
                            const int* __restrict__ flag,
                            long long E) {
    long long i      = (long long)blockIdx.x * blockDim.x + threadIdx.x;
    long long stride = (long long)gridDim.x * blockDim.x;
    const int is64 = *flag;  // uniform branch
    if (is64) {
        const long long* e64 = (const long long*)ei;
        for (long long e = i; e < E; e += stride) {
            int s = (int)e64[e];
            int d = (int)e64[E + e];
            atomicAdd(&packed[d], (double)h2[s] + PACK_SCALE);
        }
    } else {
        for (long long e = i; e < E; e += stride) {
            int s = ei[e];
            int d = ei[E + e];
            atomicAdd(&packed[d], (double)h2[s] + PACK_SCALE);
        }
    }
}

__global__ void out_kernel(const double* __restrict__ packed,
                           const float* __restrict__ Wsage,
                           float* __restrict__ out,
                           int n) {
    int i = blockIdx.x * blockDim.x + threadIdx.x;
    if (i >= n) return;
    double v   = packed[i];
    double cnt = nearbyint(v * (1.0 / PACK_SCALE));   // exact: |agg|/2^20 < 0.5
    double agg = v - cnt * PACK_SCALE;
    out[i] = (float)(agg / fmax(cnt, 1.0)) * Wsage[0];
}

extern "C" void kernel_launch(void* const* d_in, const int* in_sizes, int n_in,
                              void* d_out, int out_size, void* d_ws, size_t ws_size,
                              hipStream_t stream) {
    const float* x     = (const float*)d_in[0];
    const int*   ei    = (const int*)d_in[1];
    const float* W1    = (const float*)d_in[2];
    const float* b1    = (const float*)d_in[3];
    const float* W2    = (const float*)d_in[4];
    const float* b2    = (const float*)d_in[5];
    const float* Wsage = (const float*)d_in[6];

    const int       n = in_sizes[0];                 // 1,000,000
    const long long E = (long long)in_sizes[1] / 2;  // 32,000,000

    double* packed = (double*)d_ws;
    int*    flag   = (int*)(packed + n);
    float*  h2     = (float*)d_out;  // reuse output buffer as h2 scratch

    detect_dtype_kernel<<<1, 64, 0, stream>>>(ei, flag);

    {
        int threads = 256;
        int blocks  = (n + threads - 1) / threads;
        node_kernel<<<blocks, threads, 0, stream>>>(x, W1, b1, W2, b2, h2, packed, n);
    }
    {
        int threads = 256;
        int blocks  = 4096;  // grid-stride; atomic-rate-bound, give scheduler room
        edge_kernel<<<blocks, threads, 0, stream>>>(ei, h2, packed, flag, E);
    }
    {
        int threads = 256;
        int blocks  = (n + threads - 1) / threads;
        out_kernel<<<blocks, threads, 0, stream>>>(packed, Wsage, (float*)d_out, n);
    }
}

// Round 3
// 1277.172 us; speedup vs baseline: 2.4081x; 1.0862x over previous
//
#include <hip/hip_runtime.h>

// N=1e6 nodes, E=32e6 edges.
// out[i] = (sum_{e: dst=i} h2[src_e]) / max(deg_in(i),1) * Wsage
// h2[v] = sum_j W2[j]*relu(W1[j]*x[v]+b1[j]) + b2
//
// R2: replace 32M random global atomics (atomic-rate wall, ~23 G/s) with a
// 1-level counting sort by dst>>10 into 1024 bins, then per-bin LDS
// aggregation. Zero contended global atomics.
//
// ws layout (binned path):
//   [0, E*8)                      entries: {f32 v | dlow<<32}
//   [E*8, E*8 + NBLK*NBINS*4)     blockhist -> (in-place) column-exclusive prefix
//   then int coltotal[NBINS], int binbase[NBINS+1], int flag
// Fallback path (ws too small): double packed[N], int flag  (R1 scheme).

#define NBINS  1024
#define BSHIFT 10
#define BMASK  1023
#define NBLK   1024

// ---- dtype probe: int64 edge_index => every odd 32-bit word is 0 ----
__global__ void detect_dtype_kernel(const int* __restrict__ ei, int* __restrict__ flag) {
    if (threadIdx.x == 0 && blockIdx.x == 0) {
        int is64 = 1;
        for (int i = 1; i < 256; i += 2) {
            if (ei[i] != 0) { is64 = 0; break; }
        }
        *flag = is64;
    }
}

__global__ void node_kernel(const float* __restrict__ x,
                            const float* __restrict__ W1,
                            const float* __restrict__ b1,
                            const float* __restrict__ W2,
                            const float* __restrict__ b2,
                            float* __restrict__ h2,
                            int n) {
    int i = blockIdx.x * blockDim.x + threadIdx.x;
    if (i >= n) return;
    float xi = x[i];
    float acc = b2[0];
#pragma unroll
    for (int j = 0; j < 4; ++j) {
        float t = fmaxf(W1[j] * xi + b1[j], 0.0f);
        acc += W2[j] * t;
    }
    h2[i] = acc;
}

// ---------------- binned path ----------------

// P0: per-block histogram of dst bins.
__global__ void hist_kernel(const int* __restrict__ ei,
                            int* __restrict__ blockhist,
                            const int* __restrict__ flag,
                            long long E, long long chunk) {
    __shared__ int hist[NBINS];
    int t = threadIdx.x;
    for (int i = t; i < NBINS; i += blockDim.x) hist[i] = 0;
    __syncthreads();
    long long start = (long long)blockIdx.x * chunk;
    long long end   = start + chunk; if (end > E) end = E;
    const int is64 = *flag;
    if (is64) {
        const long long* e64 = (const long long*)ei;
        for (long long e = start + t; e < end; e += blockDim.x) {
            int d = (int)e64[E + e];
            atomicAdd(&hist[d >> BSHIFT], 1);
        }
    } else {
        for (long long e = start + t; e < end; e += blockDim.x) {
            int d = ei[E + e];
            atomicAdd(&hist[d >> BSHIFT], 1);
        }
    }
    __syncthreads();
    int* row = blockhist + (long long)blockIdx.x * NBINS;
    for (int i = t; i < NBINS; i += blockDim.x) row[i] = hist[i];
}

// S1: per-bin column exclusive scan over blocks (in place), coltotal out.
__global__ void scan_cols_kernel(int* __restrict__ blockhist,
                                 int* __restrict__ coltotal) {
    int bin = blockIdx.x;
    int t   = threadIdx.x;              // 256 threads
    const int per = NBLK / 256;         // 4
    __shared__ int tsum[256];
    int vals[per];
    int s = 0;
#pragma unroll
    for (int k = 0; k < per; ++k) {
        vals[k] = blockhist[(long long)(t * per + k) * NBINS + bin];
        s += vals[k];
    }
    tsum[t] = s;
    __syncthreads();
    if (t == 0) {
        int run = 0;
        for (int i = 0; i < 256; ++i) { int tmp = tsum[i]; tsum[i] = run; run += tmp; }
        coltotal[bin] = run;
    }
    __syncthreads();
    int excl = tsum[t];
#pragma unroll
    for (int k = 0; k < per; ++k) {
        blockhist[(long long)(t * per + k) * NBINS + bin] = excl;
        excl += vals[k];
    }
}

// S2: exclusive scan over coltotal -> binbase[NBINS+1].
__global__ void scan_base_kernel(const int* __restrict__ coltotal,
                                 int* __restrict__ binbase) {
    int t = threadIdx.x;                // 256 threads
    const int per = NBINS / 256;        // 4
    __shared__ int tsum[256];
    int vals[per];
    int s = 0;
#pragma unroll
    for (int k = 0; k < per; ++k) { vals[k] = coltotal[t * per + k]; s += vals[k]; }
    tsum[t] = s;
    __syncthreads();
    if (t == 0) {
        int run = 0;
        for (int i = 0; i < 256; ++i) { int tmp = tsum[i]; tsum[i] = run; run += tmp; }
        binbase[NBINS] = run;
    }
    __syncthreads();
    int excl = tsum[t];
#pragma unroll
    for (int k = 0; k < per; ++k) {
        binbase[t * per + k] = excl;
        excl += vals[k];
    }
}

// P1: scatter entries {v, dlow} into bin runs. LDS cursors, no global atomics.
__global__ void scatter_kernel(const int* __restrict__ ei,
                               const float* __restrict__ h2,
                               const int* __restrict__ blockhist,  // col-excl prefix
                               const int* __restrict__ binbase,
                               unsigned long long* __restrict__ entries,
                               const int* __restrict__ flag,
                               long long E, long long chunk) {
    __shared__ int cur[NBINS];
    int t = threadIdx.x;
    const int* row = blockhist + (long long)blockIdx.x * NBINS;
    for (int i = t; i < NBINS; i += blockDim.x) cur[i] = binbase[i] + row[i];
    __syncthreads();
    long long start = (long long)blockIdx.x * chunk;
    long long end   = start + chunk; if (end > E) end = E;
    const int is64 = *flag;
    if (is64) {
        const long long* e64 = (const long long*)ei;
        for (long long e = start + t; e < end; e += blockDim.x) {
            int s = (int)e64[e];
            int d = (int)e64[E + e];
            float v = h2[s];
            int slot = atomicAdd(&cur[d >> BSHIFT], 1);
            entries[slot] = (unsigned long long)__float_as_uint(v)
                          | ((unsigned long long)(d & BMASK) << 32);
        }
    } else {
        for (long long e = start + t; e < end; e += blockDim.x) {
            int s = ei[e];
            int d = ei[E + e];
            float v = h2[s];
            int slot = atomicAdd(&cur[d >> BSHIFT], 1);
            entries[slot] = (unsigned long long)__float_as_uint(v)
                          | ((unsigned long long)(d & BMASK) << 32);
        }
    }
}

// P2: per-bin aggregation in LDS, write final out.
__global__ void aggregate_kernel(const unsigned long long* __restrict__ entries,
                                 const int* __restrict__ binbase,
                                 const float* __restrict__ Wsage,
                                 float* __restrict__ out,
                                 int n) {
    __shared__ float ssum[NBINS];
    __shared__ int   scnt[NBINS];
    int bin = blockIdx.x;
    int t   = threadIdx.x;
    for (int i = t; i < NBINS; i += blockDim.x) { ssum[i] = 0.0f; scnt[i] = 0; }
    __syncthreads();
    int lo = binbase[bin], hi = binbase[bin + 1];
    for (int e = lo + t; e < hi; e += blockDim.x) {
        unsigned long long ent = entries[e];
        float v  = __uint_as_float((unsigned)ent);
        int dlow = (int)(ent >> 32);
        atomicAdd(&ssum[dlow], v);
        atomicAdd(&scnt[dlow], 1);
    }
    __syncthreads();
    float w = Wsage[0];
    int base = bin << BSHIFT;
    for (int i = t; i < NBINS; i += blockDim.x) {
        int node = base + i;
        if (node < n) {
            float c = (float)scnt[i];
            out[node] = ssum[i] / fmaxf(c, 1.0f) * w;
        }
    }
}

// ---------------- fallback path (R1 packed-atomic) ----------------

#define PACK_SCALE 1048576.0  // 2^20

__global__ void zero_packed_kernel(double* __restrict__ packed, int n) {
    int i = blockIdx.x * blockDim.x + threadIdx.x;
    if (i < n) packed[i] = 0.0;
}

__global__ void edge_atomic_kernel(const int* __restrict__ ei,
                                   const float* __restrict__ h2,
                                   double* __restrict__ packed,
                                   const int* __restrict__ flag,
                                   long long E) {
    long long i      = (long long)blockIdx.x * blockDim.x + threadIdx.x;
    long long stride = (long long)gridDim.x * blockDim.x;
    const int is64 = *flag;
    if (is64) {
        const long long* e64 = (const long long*)ei;
        for (long long e = i; e < E; e += stride) {
            int s = (int)e64[e];
            int d = (int)e64[E + e];
            atomicAdd(&packed[d], (double)h2[s] + PACK_SCALE);
        }
    } else {
        for (long long e = i; e < E; e += stride) {
            int s = ei[e];
            int d = ei[E + e];
            atomicAdd(&packed[d], (double)h2[s] + PACK_SCALE);
        }
    }
}

__global__ void out_packed_kernel(const double* __restrict__ packed,
                                  const float* __restrict__ Wsage,
                                  float* __restrict__ out,
                                  int n) {
    int i = blockIdx.x * blockDim.x + threadIdx.x;
    if (i >= n) return;
    double v   = packed[i];
    double cnt = nearbyint(v * (1.0 / PACK_SCALE));
    double agg = v - cnt * PACK_SCALE;
    out[i] = (float)(agg / fmax(cnt, 1.0)) * Wsage[0];
}

extern "C" void kernel_launch(void* const* d_in, const int* in_sizes, int n_in,
                              void* d_out, int out_size, void* d_ws, size_t ws_size,
                              hipStream_t stream) {
    const float* x     = (const float*)d_in[0];
    const int*   ei    = (const int*)d_in[1];
    const float* W1    = (const float*)d_in[2];
    const float* b1    = (const float*)d_in[3];
    const float* W2    = (const float*)d_in[4];
    const float* b2    = (const float*)d_in[5];
    const float* Wsage = (const float*)d_in[6];

    const int       n = in_sizes[0];                 // 1,000,000
    const long long E = (long long)in_sizes[1] / 2;  // 32,000,000

    float* h2 = (float*)d_out;  // reuse output buffer as h2 scratch

    // binned-path workspace requirement
    const size_t entries_b = (size_t)E * 8;
    const size_t hist_b    = (size_t)NBLK * NBINS * 4;
    const size_t need      = entries_b + hist_b + (size_t)NBINS * 4
                           + (size_t)(NBINS + 1) * 4 + 64;

    {
        int threads = 256;
        int blocks  = (n + threads - 1) / threads;
        node_kernel<<<blocks, threads, 0, stream>>>(x, W1, b1, W2, b2, h2, n);
    }

    if (ws_size >= need) {
        unsigned long long* entries  = (unsigned long long*)d_ws;
        int* blockhist = (int*)((char*)d_ws + entries_b);
        int* coltotal  = blockhist + (size_t)NBLK * NBINS;
        int* binbase   = coltotal + NBINS;
        int* flag      = binbase + (NBINS + 1);

        detect_dtype_kernel<<<1, 64, 0, stream>>>(ei, flag);

        long long chunk = (E + NBLK - 1) / NBLK;
        hist_kernel<<<NBLK, 256, 0, stream>>>(ei, blockhist, flag, E, chunk);
        scan_cols_kernel<<<NBINS, 256, 0, stream>>>(blockhist, coltotal);
        scan_base_kernel<<<1, 256, 0, stream>>>(coltotal, binbase);
        scatter_kernel<<<NBLK, 256, 0, stream>>>(ei, h2, blockhist, binbase,
                                                 entries, flag, E, chunk);
        aggregate_kernel<<<NBINS, 256, 0, stream>>>(entries, binbase, Wsage,
                                                    (float*)d_out, n);
    } else {
        // fallback: R1 packed-atomic path (needs 8N+4 bytes)
        double* packed = (double*)d_ws;
        int*    flag   = (int*)(packed + n);

        detect_dtype_kernel<<<1, 64, 0, stream>>>(ei, flag);
        {
            int threads = 256;
            int blocks  = (n + threads - 1) / threads;
            zero_packed_kernel<<<blocks, threads, 0, stream>>>(packed, n);
        }
        edge_atomic_kernel<<<4096, 256, 0, stream>>>(ei, h2, packed, flag, E);
        {
            int threads = 256;
            int blocks  = (n + threads - 1) / threads;
            out_packed_kernel<<<blocks, threads, 0, stream>>>(packed, Wsage,
                                                              (float*)d_out, n);
        }
    }
}

// Round 4
// 1136.974 us; speedup vs baseline: 2.7050x; 1.1233x over previous
//
#include <hip/hip_runtime.h>
#include <hip/hip_fp16.h>

// N=1e6 nodes, E=32e6 edges.
// out[i] = (sum_{e: dst=i} h2[src_e]) / max(deg_in(i),1) * Wsage
// h2[v] = sum_j W2[j]*relu(W1[j]*x[v]+b1[j]) + b2
//
// R3: counting-sort by dst>>12 into 256 bins (4096 nodes/bin).
//  - 4-byte entries: (dlow:12)<<16 | fp16(h2[src])  -> half the scatter traffic
//  - 256 write frontiers/block (32KB) -> L2 write-combining works (R2's 1024
//    frontiers = 4MB/XCD thrashed; WRITE was 946MB for 256MB of payload)
//  - nontemporal loads for ei / entries streams so L2 keeps frontiers + h2
//  - aggregate: 1 block/bin, LDS sum/cnt[4096], pure streaming read.
//
// ws layout: entries uint[E]; blockhist int[NBLK*NBINS]; coltotal[NBINS];
//            binbase[NBINS+1]; h2 float[n]; flag int.
// Fallback (ws too small): R1 packed f64-atomic path.

#define NBINS  256
#define BSHIFT 12
#define DMASK  4095
#define NBLK   1024

// ---- dtype probe: int64 edge_index => every odd 32-bit word is 0 ----
__global__ void detect_dtype_kernel(const int* __restrict__ ei, int* __restrict__ flag) {
    if (threadIdx.x == 0 && blockIdx.x == 0) {
        int is64 = 1;
        for (int i = 1; i < 256; i += 2) {
            if (ei[i] != 0) { is64 = 0; break; }
        }
        *flag = is64;
    }
}

__global__ void node_kernel(const float* __restrict__ x,
                            const float* __restrict__ W1,
                            const float* __restrict__ b1,
                            const float* __restrict__ W2,
                            const float* __restrict__ b2,
                            float* __restrict__ h2,
                            int n) {
    int i = blockIdx.x * blockDim.x + threadIdx.x;
    if (i >= n) return;
    float xi = x[i];
    float acc = b2[0];
#pragma unroll
    for (int j = 0; j < 4; ++j) {
        float t = fmaxf(W1[j] * xi + b1[j], 0.0f);
        acc += W2[j] * t;
    }
    h2[i] = acc;
}

// P0: per-block histogram of dst bins (nontemporal dst stream).
__global__ void hist_kernel(const int* __restrict__ ei,
                            int* __restrict__ blockhist,
                            const int* __restrict__ flag,
                            long long E, long long chunk) {
    __shared__ int hist[NBINS];
    int t = threadIdx.x;
    for (int i = t; i < NBINS; i += blockDim.x) hist[i] = 0;
    __syncthreads();
    long long start = (long long)blockIdx.x * chunk;
    long long end   = start + chunk; if (end > E) end = E;
    const int is64 = *flag;
    if (is64) {
        const long long* e64 = (const long long*)ei;
        for (long long e = start + t; e < end; e += blockDim.x) {
            int d = (int)__builtin_nontemporal_load(&e64[E + e]);
            atomicAdd(&hist[d >> BSHIFT], 1);
        }
    } else {
        for (long long e = start + t; e < end; e += blockDim.x) {
            int d = __builtin_nontemporal_load(&ei[E + e]);
            atomicAdd(&hist[d >> BSHIFT], 1);
        }
    }
    __syncthreads();
    int* row = blockhist + (long long)blockIdx.x * NBINS;
    for (int i = t; i < NBINS; i += blockDim.x) row[i] = hist[i];
}

// S1: per-bin column exclusive scan over blocks (in place), coltotal out.
__global__ void scan_cols_kernel(int* __restrict__ blockhist,
                                 int* __restrict__ coltotal) {
    int bin = blockIdx.x;               // NBINS blocks
    int t   = threadIdx.x;              // 256 threads
    const int per = NBLK / 256;         // 4
    __shared__ int tsum[256];
    int vals[per];
    int s = 0;
#pragma unroll
    for (int k = 0; k < per; ++k) {
        vals[k] = blockhist[(long long)(t * per + k) * NBINS + bin];
        s += vals[k];
    }
    tsum[t] = s;
    __syncthreads();
    if (t == 0) {
        int run = 0;
        for (int i = 0; i < 256; ++i) { int tmp = tsum[i]; tsum[i] = run; run += tmp; }
        coltotal[bin] = run;
    }
    __syncthreads();
    int excl = tsum[t];
#pragma unroll
    for (int k = 0; k < per; ++k) {
        blockhist[(long long)(t * per + k) * NBINS + bin] = excl;
        excl += vals[k];
    }
}

// S2: exclusive scan over coltotal -> binbase[NBINS+1]. (1 block, NBINS<=256)
__global__ void scan_base_kernel(const int* __restrict__ coltotal,
                                 int* __restrict__ binbase) {
    int t = threadIdx.x;                // 256 threads, per=1
    __shared__ int tsum[256];
    int v = (t < NBINS) ? coltotal[t] : 0;
    tsum[t] = v;
    __syncthreads();
    if (t == 0) {
        int run = 0;
        for (int i = 0; i < 256; ++i) { int tmp = tsum[i]; tsum[i] = run; run += tmp; }
        binbase[NBINS] = run;
    }
    __syncthreads();
    if (t < NBINS) binbase[t] = tsum[t];
}

// P1: scatter 4B entries {dlow:12 | fp16(h2[src])} into bin runs.
__global__ void scatter_kernel(const int* __restrict__ ei,
                               const float* __restrict__ h2,
                               const int* __restrict__ blockhist,  // col-excl prefix
                               const int* __restrict__ binbase,
                               unsigned int* __restrict__ entries,
                               const int* __restrict__ flag,
                               long long E, long long chunk) {
    __shared__ int cur[NBINS];
    int t = threadIdx.x;
    const int* row = blockhist + (long long)blockIdx.x * NBINS;
    for (int i = t; i < NBINS; i += blockDim.x) cur[i] = binbase[i] + row[i];
    __syncthreads();
    long long start = (long long)blockIdx.x * chunk;
    long long end   = start + chunk; if (end > E) end = E;
    const int is64 = *flag;
    if (is64) {
        const long long* e64 = (const long long*)ei;
        for (long long e = start + t; e < end; e += blockDim.x) {
            int s = (int)__builtin_nontemporal_load(&e64[e]);
            int d = (int)__builtin_nontemporal_load(&e64[E + e]);
            float v = h2[s];                       // temporal: L2/L3-resident
            unsigned int hb = (unsigned int)__half_as_ushort(__float2half(v));
            unsigned int entry = ((unsigned int)(d & DMASK) << 16) | hb;
            int slot = atomicAdd(&cur[d >> BSHIFT], 1);
            entries[slot] = entry;                 // temporal: want combining
        }
    } else {
        for (long long e = start + t; e < end; e += blockDim.x) {
            int s = __builtin_nontemporal_load(&ei[e]);
            int d = __builtin_nontemporal_load(&ei[E + e]);
            float v = h2[s];
            unsigned int hb = (unsigned int)__half_as_ushort(__float2half(v));
            unsigned int entry = ((unsigned int)(d & DMASK) << 16) | hb;
            int slot = atomicAdd(&cur[d >> BSHIFT], 1);
            entries[slot] = entry;
        }
    }
}

// P2: per-bin aggregation in LDS (4096 nodes/bin), write final out.
__global__ void __launch_bounds__(1024)
aggregate_kernel(const unsigned int* __restrict__ entries,
                 const int* __restrict__ binbase,
                 const float* __restrict__ Wsage,
                 float* __restrict__ out,
                 int n) {
    __shared__ float ssum[4096];
    __shared__ int   scnt[4096];
    int bin = blockIdx.x;
    int t   = threadIdx.x;
    for (int i = t; i < 4096; i += blockDim.x) { ssum[i] = 0.0f; scnt[i] = 0; }
    __syncthreads();
    int lo = binbase[bin], hi = binbase[bin + 1];
    for (int e = lo + t; e < hi; e += blockDim.x) {
        unsigned int ent = __builtin_nontemporal_load(&entries[e]);
        int dlow = (int)(ent >> 16);
        float v  = __half2float(__ushort_as_half((unsigned short)(ent & 0xFFFFu)));
        atomicAdd(&ssum[dlow], v);
        atomicAdd(&scnt[dlow], 1);
    }
    __syncthreads();
    float w = Wsage[0];
    int base = bin << BSHIFT;
    for (int i = t; i < 4096; i += blockDim.x) {
        int node = base + i;
        if (node < n) {
            float c = (float)scnt[i];
            out[node] = ssum[i] / fmaxf(c, 1.0f) * w;
        }
    }
}

// ---------------- fallback path (R1 packed-atomic) ----------------

#define PACK_SCALE 1048576.0  // 2^20

__global__ void zero_packed_kernel(double* __restrict__ packed, int n) {
    int i = blockIdx.x * blockDim.x + threadIdx.x;
    if (i < n) packed[i] = 0.0;
}

__global__ void edge_atomic_kernel(const int* __restrict__ ei,
                                   const float* __restrict__ h2,
                                   double* __restrict__ packed,
                                   const int* __restrict__ flag,
                                   long long E) {
    long long i      = (long long)blockIdx.x * blockDim.x + threadIdx.x;
    long long stride = (long long)gridDim.x * blockDim.x;
    const int is64 = *flag;
    if (is64) {
        const long long* e64 = (const long long*)ei;
        for (long long e = i; e < E; e += stride) {
            int s = (int)e64[e];
            int d = (int)e64[E + e];
            atomicAdd(&packed[d], (double)h2[s] + PACK_SCALE);
        }
    } else {
        for (long long e = i; e < E; e += stride) {
            int s = ei[e];
            int d = ei[E + e];
            atomicAdd(&packed[d], (double)h2[s] + PACK_SCALE);
        }
    }
}

__global__ void out_packed_kernel(const double* __restrict__ packed,
                                  const float* __restrict__ Wsage,
                                  float* __restrict__ out,
                                  int n) {
    int i = blockIdx.x * blockDim.x + threadIdx.x;
    if (i >= n) return;
    double v   = packed[i];
    double cnt = nearbyint(v * (1.0 / PACK_SCALE));
    double agg = v - cnt * PACK_SCALE;
    out[i] = (float)(agg / fmax(cnt, 1.0)) * Wsage[0];
}

extern "C" void kernel_launch(void* const* d_in, const int* in_sizes, int n_in,
                              void* d_out, int out_size, void* d_ws, size_t ws_size,
                              hipStream_t stream) {
    const float* x     = (const float*)d_in[0];
    const int*   ei    = (const int*)d_in[1];
    const float* W1    = (const float*)d_in[2];
    const float* b1    = (const float*)d_in[3];
    const float* W2    = (const float*)d_in[4];
    const float* b2    = (const float*)d_in[5];
    const float* Wsage = (const float*)d_in[6];

    const int       n = in_sizes[0];                 // 1,000,000
    const long long E = (long long)in_sizes[1] / 2;  // 32,000,000

    // binned-path workspace layout
    const size_t entries_b = (size_t)E * 4;
    const size_t hist_b    = (size_t)NBLK * NBINS * 4;
    const size_t need      = entries_b + hist_b + (size_t)NBINS * 4
                           + (size_t)(NBINS + 1) * 4 + (size_t)n * 4 + 64;

    if (ws_size >= need) {
        unsigned int* entries = (unsigned int*)d_ws;
        int*   blockhist = (int*)((char*)d_ws + entries_b);
        int*   coltotal  = blockhist + (size_t)NBLK * NBINS;
        int*   binbase   = coltotal + NBINS;
        float* h2        = (float*)(binbase + (NBINS + 1));
        int*   flag      = (int*)(h2 + n);

        detect_dtype_kernel<<<1, 64, 0, stream>>>(ei, flag);
        {
            int threads = 256;
            int blocks  = (n + threads - 1) / threads;
            node_kernel<<<blocks, threads, 0, stream>>>(x, W1, b1, W2, b2, h2, n);
        }
        long long chunk = (E + NBLK - 1) / NBLK;
        hist_kernel<<<NBLK, 256, 0, stream>>>(ei, blockhist, flag, E, chunk);
        scan_cols_kernel<<<NBINS, 256, 0, stream>>>(blockhist, coltotal);
        scan_base_kernel<<<1, 256, 0, stream>>>(coltotal, binbase);
        scatter_kernel<<<NBLK, 256, 0, stream>>>(ei, h2, blockhist, binbase,
                                                 entries, flag, E, chunk);
        aggregate_kernel<<<NBINS, 1024, 0, stream>>>(entries, binbase, Wsage,
                                                     (float*)d_out, n);
    } else {
        // fallback: R1 packed-atomic path (needs 8N + N*4 + 4 bytes)
        double* packed = (double*)d_ws;
        float*  h2     = (float*)d_out;
        int*    flag   = (int*)(packed + n);

        detect_dtype_kernel<<<1, 64, 0, stream>>>(ei, flag);
        {
            int threads = 256;
            int blocks  = (n + threads - 1) / threads;
            node_kernel<<<blocks, threads, 0, stream>>>(x, W1, b1, W2, b2, h2, n);
            zero_packed_kernel<<<blocks, threads, 0, stream>>>(packed, n);
        }
        edge_atomic_kernel<<<4096, 256, 0, stream>>>(ei, h2, packed, flag, E);
        {
            int threads = 256;
            int blocks  = (n + threads - 1) / threads;
            out_packed_kernel<<<blocks, threads, 0, stream>>>(packed, Wsage,
                                                              (float*)d_out, n);
        }
    }
}

// Round 5
// 580.949 us; speedup vs baseline: 5.2939x; 1.9571x over previous
//
#include <hip/hip_runtime.h>
#include <hip/hip_fp16.h>

// N=1e6 nodes, E=32e6 edges.
// out[i] = (sum_{e: dst=i} h2[src_e]) / max(deg_in(i),1) * Wsage
// h2[v] = sum_j W2[j]*relu(W1[j]*x[v]+b1[j]) + b2
//
// R4: counting-sort by dst>>12 into 256 bins, but the scatter now does a
// block-level tile sort (8192 edges/tile) in LDS and copies out bin-sorted
// runs -> global writes are coalesced full sectors BY CONSTRUCTION.
// R3's lesson: relying on L2 write-combining fails when the aggregate write
// frontier (resident_blocks x NBINS x 128B) exceeds the 4MB per-XCD L2
// (WRITE was 771MB for 128MB of payload). Now only the straddle sector per
// (block,bin) is partial: 64x256x32B = 512KB/XCD, L2-resident.
//
// ws layout: entries uint[E]; blockhist int[NBLK*NBINS]; coltotal[NBINS];
//            binbase[NBINS+1]; h2 float[n]; flag int.
// Fallback (ws too small): R1 packed f64-atomic path.

#define NBINS   256
#define BSHIFT  12
#define DMASK   4095
#define NBLK    512
#define STHREADS 512
#define EPT     16
#define TILE    (STHREADS * EPT)   // 8192

// ---- dtype probe: int64 edge_index => every odd 32-bit word is 0 ----
__global__ void detect_dtype_kernel(const int* __restrict__ ei, int* __restrict__ flag) {
    if (threadIdx.x == 0 && blockIdx.x == 0) {
        int is64 = 1;
        for (int i = 1; i < 256; i += 2) {
            if (ei[i] != 0) { is64 = 0; break; }
        }
        *flag = is64;
    }
}

__global__ void node_kernel(const float* __restrict__ x,
                            const float* __restrict__ W1,
                            const float* __restrict__ b1,
                            const float* __restrict__ W2,
                            const float* __restrict__ b2,
                            float* __restrict__ h2,
                            int n) {
    int i = blockIdx.x * blockDim.x + threadIdx.x;
    if (i >= n) return;
    float xi = x[i];
    float acc = b2[0];
#pragma unroll
    for (int j = 0; j < 4; ++j) {
        float t = fmaxf(W1[j] * xi + b1[j], 0.0f);
        acc += W2[j] * t;
    }
    h2[i] = acc;
}

// P0: per-block histogram of dst bins (same chunking as scatter!).
__global__ void hist_kernel(const int* __restrict__ ei,
                            int* __restrict__ blockhist,
                            const int* __restrict__ flag,
                            long long E, long long chunk) {
    __shared__ int hist[NBINS];
    int t = threadIdx.x;
    for (int i = t; i < NBINS; i += blockDim.x) hist[i] = 0;
    __syncthreads();
    long long start = (long long)blockIdx.x * chunk;
    long long end   = start + chunk; if (end > E) end = E;
    const int is64 = *flag;
    if (is64) {
        const long long* e64 = (const long long*)ei;
        for (long long e = start + t; e < end; e += blockDim.x) {
            int d = (int)__builtin_nontemporal_load(&e64[E + e]);
            atomicAdd(&hist[d >> BSHIFT], 1);
        }
    } else {
        for (long long e = start + t; e < end; e += blockDim.x) {
            int d = __builtin_nontemporal_load(&ei[E + e]);
            atomicAdd(&hist[d >> BSHIFT], 1);
        }
    }
    __syncthreads();
    int* row = blockhist + (long long)blockIdx.x * NBINS;
    for (int i = t; i < NBINS; i += blockDim.x) row[i] = hist[i];
}

// S1: per-bin column exclusive scan over blocks (in place), coltotal out.
__global__ void scan_cols_kernel(int* __restrict__ blockhist,
                                 int* __restrict__ coltotal) {
    int bin = blockIdx.x;               // NBINS blocks
    int t   = threadIdx.x;              // 256 threads
    const int per = NBLK / 256;         // 2
    __shared__ int tsum[256];
    int vals[per];
    int s = 0;
#pragma unroll
    for (int k = 0; k < per; ++k) {
        vals[k] = blockhist[(long long)(t * per + k) * NBINS + bin];
        s += vals[k];
    }
    tsum[t] = s;
    __syncthreads();
    if (t == 0) {
        int run = 0;
        for (int i = 0; i < 256; ++i) { int tmp = tsum[i]; tsum[i] = run; run += tmp; }
        coltotal[bin] = run;
    }
    __syncthreads();
    int excl = tsum[t];
#pragma unroll
    for (int k = 0; k < per; ++k) {
        blockhist[(long long)(t * per + k) * NBINS + bin] = excl;
        excl += vals[k];
    }
}

// S2: exclusive scan over coltotal -> binbase[NBINS+1]. (1 block)
__global__ void scan_base_kernel(const int* __restrict__ coltotal,
                                 int* __restrict__ binbase) {
    int t = threadIdx.x;                // 256 threads
    __shared__ int tsum[256];
    int v = (t < NBINS) ? coltotal[t] : 0;
    tsum[t] = v;
    __syncthreads();
    if (t == 0) {
        int run = 0;
        for (int i = 0; i < 256; ++i) { int tmp = tsum[i]; tsum[i] = run; run += tmp; }
        binbase[NBINS] = run;
    }
    __syncthreads();
    if (t < NBINS) binbase[t] = tsum[t];
}

// P1: tile-sorted scatter. Entries {dlow:12 | fp16(h2[src])} written in
// bin-sorted coalesced runs.
__global__ void __launch_bounds__(STHREADS)
scatter_kernel(const int* __restrict__ ei,
               const float* __restrict__ h2,
               const int* __restrict__ blockhist,  // col-excl prefix
               const int* __restrict__ binbase,
               unsigned int* __restrict__ entries,
               const int* __restrict__ flag,
               long long E, long long chunk) {
    __shared__ unsigned int  ents[TILE];
    __shared__ unsigned char binof[TILE];
    __shared__ int hist[NBINS];
    __shared__ int toff[NBINS];
    __shared__ int cur[NBINS];
    __shared__ int scanbuf[NBINS];

    int t = threadIdx.x;
    const int* row = blockhist + (long long)blockIdx.x * NBINS;
    for (int i = t; i < NBINS; i += STHREADS) cur[i] = binbase[i] + row[i];

    long long start = (long long)blockIdx.x * chunk;
    long long end   = start + chunk; if (end > E) end = E;
    const int is64 = *flag;

    for (long long tbase = start; tbase < end; tbase += TILE) {
        for (int i = t; i < NBINS; i += STHREADS) hist[i] = 0;
        __syncthreads();

        unsigned int entv[EPT];
        int bk[EPT], rk[EPT];
#pragma unroll
        for (int k = 0; k < EPT; ++k) {
            long long e = tbase + (long long)k * STHREADS + t;
            bk[k] = -1;
            if (e < end) {
                int s, d;
                if (is64) {
                    const long long* e64 = (const long long*)ei;
                    s = (int)__builtin_nontemporal_load(&e64[e]);
                    d = (int)__builtin_nontemporal_load(&e64[E + e]);
                } else {
                    s = __builtin_nontemporal_load(&ei[e]);
                    d = __builtin_nontemporal_load(&ei[E + e]);
                }
                float v = h2[s];
                entv[k] = ((unsigned int)(d & DMASK) << 16)
                        | (unsigned int)__half_as_ushort(__float2half(v));
                int b = d >> BSHIFT;
                bk[k] = b;
                rk[k] = atomicAdd(&hist[b], 1);   // rank within (tile,bin)
            }
        }
        __syncthreads();

        // exclusive scan of hist over 256 bins (Hillis-Steele)
        if (t < NBINS) scanbuf[t] = hist[t];
        __syncthreads();
        for (int off = 1; off < NBINS; off <<= 1) {
            int v = 0;
            if (t < NBINS && t >= off) v = scanbuf[t - off];
            __syncthreads();
            if (t < NBINS) scanbuf[t] += v;
            __syncthreads();
        }
        if (t < NBINS) toff[t] = scanbuf[t] - hist[t];
        __syncthreads();

        // place bin-sorted in LDS
#pragma unroll
        for (int k = 0; k < EPT; ++k) {
            if (bk[k] >= 0) {
                int slot = toff[bk[k]] + rk[k];
                ents[slot]  = entv[k];
                binof[slot] = (unsigned char)bk[k];
            }
        }
        __syncthreads();

        // coalesced copy-out: consecutive j -> consecutive global within run
        int tilecount = scanbuf[NBINS - 1];
        for (int j = t; j < tilecount; j += STHREADS) {
            int b = binof[j];
            entries[cur[b] + (j - toff[b])] = ents[j];
        }
        __syncthreads();
        if (t < NBINS) cur[t] += hist[t];
        __syncthreads();
    }
}

// P2: per-bin aggregation in LDS (4096 nodes/bin), write final out.
__global__ void __launch_bounds__(1024)
aggregate_kernel(const unsigned int* __restrict__ entries,
                 const int* __restrict__ binbase,
                 const float* __restrict__ Wsage,
                 float* __restrict__ out,
                 int n) {
    __shared__ float ssum[4096];
    __shared__ int   scnt[4096];
    int bin = blockIdx.x;
    int t   = threadIdx.x;
    for (int i = t; i < 4096; i += blockDim.x) { ssum[i] = 0.0f; scnt[i] = 0; }
    __syncthreads();
    int lo = binbase[bin], hi = binbase[bin + 1];
    for (int e = lo + t; e < hi; e += blockDim.x) {
        unsigned int ent = __builtin_nontemporal_load(&entries[e]);
        int dlow = (int)(ent >> 16);
        float v  = __half2float(__ushort_as_half((unsigned short)(ent & 0xFFFFu)));
        atomicAdd(&ssum[dlow], v);
        atomicAdd(&scnt[dlow], 1);
    }
    __syncthreads();
    float w = Wsage[0];
    int base = bin << BSHIFT;
    for (int i = t; i < 4096; i += blockDim.x) {
        int node = base + i;
        if (node < n) {
            float c = (float)scnt[i];
            out[node] = ssum[i] / fmaxf(c, 1.0f) * w;
        }
    }
}

// ---------------- fallback path (R1 packed-atomic) ----------------

#define PACK_SCALE 1048576.0  // 2^20

__global__ void zero_packed_kernel(double* __restrict__ packed, int n) {
    int i = blockIdx.x * blockDim.x + threadIdx.x;
    if (i < n) packed[i] = 0.0;
}

__global__ void edge_atomic_kernel(const int* __restrict__ ei,
                                   const float* __restrict__ h2,
                                   double* __restrict__ packed,
                                   const int* __restrict__ flag,
                                   long long E) {
    long long i      = (long long)blockIdx.x * blockDim.x + threadIdx.x;
    long long stride = (long long)gridDim.x * blockDim.x;
    const int is64 = *flag;
    if (is64) {
        const long long* e64 = (const long long*)ei;
        for (long long e = i; e < E; e += stride) {
            int s = (int)e64[e];
            int d = (int)e64[E + e];
            atomicAdd(&packed[d], (double)h2[s] + PACK_SCALE);
        }
    } else {
        for (long long e = i; e < E; e += stride) {
            int s = ei[e];
            int d = ei[E + e];
            atomicAdd(&packed[d], (double)h2[s] + PACK_SCALE);
        }
    }
}

__global__ void out_packed_kernel(const double* __restrict__ packed,
                                  const float* __restrict__ Wsage,
                                  float* __restrict__ out,
                                  int n) {
    int i = blockIdx.x * blockDim.x + threadIdx.x;
    if (i >= n) return;
    double v   = packed[i];
    double cnt = nearbyint(v * (1.0 / PACK_SCALE));
    double agg = v - cnt * PACK_SCALE;
    out[i] = (float)(agg / fmax(cnt, 1.0)) * Wsage[0];
}

extern "C" void kernel_launch(void* const* d_in, const int* in_sizes, int n_in,
                              void* d_out, int out_size, void* d_ws, size_t ws_size,
                              hipStream_t stream) {
    const float* x     = (const float*)d_in[0];
    const int*   ei    = (const int*)d_in[1];
    const float* W1    = (const float*)d_in[2];
    const float* b1    = (const float*)d_in[3];
    const float* W2    = (const float*)d_in[4];
    const float* b2    = (const float*)d_in[5];
    const float* Wsage = (const float*)d_in[6];

    const int       n = in_sizes[0];                 // 1,000,000
    const long long E = (long long)in_sizes[1] / 2;  // 32,000,000

    // binned-path workspace layout
    const size_t entries_b = (size_t)E * 4;
    const size_t hist_b    = (size_t)NBLK * NBINS * 4;
    const size_t need      = entries_b + hist_b + (size_t)NBINS * 4
                           + (size_t)(NBINS + 1) * 4 + (size_t)n * 4 + 64;

    if (ws_size >= need) {
        unsigned int* entries = (unsigned int*)d_ws;
        int*   blockhist = (int*)((char*)d_ws + entries_b);
        int*   coltotal  = blockhist + (size_t)NBLK * NBINS;
        int*   binbase   = coltotal + NBINS;
        float* h2        = (float*)(binbase + (NBINS + 1));
        int*   flag      = (int*)(h2 + n);

        detect_dtype_kernel<<<1, 64, 0, stream>>>(ei, flag);
        {
            int threads = 256;
            int blocks  = (n + threads - 1) / threads;
            node_kernel<<<blocks, threads, 0, stream>>>(x, W1, b1, W2, b2, h2, n);
        }
        long long chunk = (E + NBLK - 1) / NBLK;
        hist_kernel<<<NBLK, 256, 0, stream>>>(ei, blockhist, flag, E, chunk);
        scan_cols_kernel<<<NBINS, 256, 0, stream>>>(blockhist, coltotal);
        scan_base_kernel<<<1, 256, 0, stream>>>(coltotal, binbase);
        scatter_kernel<<<NBLK, STHREADS, 0, stream>>>(ei, h2, blockhist, binbase,
                                                      entries, flag, E, chunk);
        aggregate_kernel<<<NBINS, 1024, 0, stream>>>(entries, binbase, Wsage,
                                                     (float*)d_out, n);
    } else {
        // fallback: R1 packed-atomic path
        double* packed = (double*)d_ws;
        float*  h2     = (float*)d_out;
        int*    flag   = (int*)(packed + n);

        detect_dtype_kernel<<<1, 64, 0, stream>>>(ei, flag);
        {
            int threads = 256;
            int blocks  = (n + threads - 1) / threads;
            node_kernel<<<blocks, threads, 0, stream>>>(x, W1, b1, W2, b2, h2, n);
            zero_packed_kernel<<<blocks, threads, 0, stream>>>(packed, n);
        }
        edge_atomic_kernel<<<4096, 256, 0, stream>>>(ei, h2, packed, flag, E);
        {
            int threads = 256;
            int blocks  = (n + threads - 1) / threads;
            out_packed_kernel<<<blocks, threads, 0, stream>>>(packed, Wsage,
                                                              (float*)d_out, n);
        }
    }
}

// Round 6
// 401.175 us; speedup vs baseline: 7.6662x; 1.4481x over previous
//
#include <hip/hip_runtime.h>
#include <hip/hip_fp16.h>

// N=1e6 nodes, E=32e6 edges.
// out[i] = (sum_{e: dst=i} h2[src_e]) / max(deg_in(i),1) * Wsage
// h2[v] = sum_j W2[j]*relu(W1[j]*x[v]+b1[j]) + b2
//
// R5: ONE pass over edge_index. Each block sorts 8192-edge tiles by
// dst>>12 (256 bins) in LDS and writes the sorted tile to its own fixed
// global slot (block-sequential => coalesced full sectors, no cross-block
// offsets needed => the R4 hist/scan passes are deleted). Per-tile bin
// boundaries go to a bin-major index[257][NTILES] so the aggregate kernel
// streams its bin's run table contiguously.
//  - h2 kept as fp16 table (2 MB): halves gather footprint, L2-resident.
//  - scatter phases (load-all/gather-all/rank-all) with static-indexed
//    arrays: R4's VGPR=40 showed the compiler serialized the pipeline.
//  - aggregate: 1 block/bin, 2 tiles per wave (32-lane halves), runs are
//    contiguous ~128B reads; LDS sum/cnt[4096]; final out write.
//
// ws layout: entries uint[NTILES*TILE]; index int[257*NTILES];
//            h2f16 ushort[n]; flag int.
// Fallback (ws too small): R1 packed f64-atomic path.

#define NBINS    256
#define BSHIFT   12
#define DMASK    4095
#define NBLK     512
#define STHREADS 512
#define EPT      16
#define TILE     (STHREADS * EPT)   // 8192

// ---- dtype probe: int64 edge_index => every odd 32-bit word is 0 ----
__global__ void detect_dtype_kernel(const int* __restrict__ ei, int* __restrict__ flag) {
    if (threadIdx.x == 0 && blockIdx.x == 0) {
        int is64 = 1;
        for (int i = 1; i < 256; i += 2) {
            if (ei[i] != 0) { is64 = 0; break; }
        }
        *flag = is64;
    }
}

__global__ void node_kernel(const float* __restrict__ x,
                            const float* __restrict__ W1,
                            const float* __restrict__ b1,
                            const float* __restrict__ W2,
                            const float* __restrict__ b2,
                            unsigned short* __restrict__ h2f16,
                            int n) {
    int i = blockIdx.x * blockDim.x + threadIdx.x;
    if (i >= n) return;
    float xi = x[i];
    float acc = b2[0];
#pragma unroll
    for (int j = 0; j < 4; ++j) {
        float t = fmaxf(W1[j] * xi + b1[j], 0.0f);
        acc += W2[j] * t;
    }
    h2f16[i] = __half_as_ushort(__float2half(acc));
}

// P1: one-pass tile-sorted scatter into block-private slots + bin-major index.
__global__ void __launch_bounds__(STHREADS)
scatter_tile_kernel(const int* __restrict__ ei,
                    const unsigned short* __restrict__ h2f16,
                    unsigned int* __restrict__ entries,
                    int* __restrict__ index,   // [257][ntiles]
                    const int* __restrict__ flag,
                    long long E, long long chunk, int tpb, int ntiles) {
    __shared__ unsigned int ents[TILE];
    __shared__ int hist[NBINS];
    __shared__ int scanbuf[NBINS];
    __shared__ int toff[NBINS];

    const int t = threadIdx.x;
    long long start = (long long)blockIdx.x * chunk;
    long long end   = start + chunk; if (end > E) end = E;
    const int is64 = *flag;
    const long long* e64 = (const long long*)ei;

    int ti = 0;
    for (long long tbase = start; tbase < end; tbase += TILE, ++ti) {
        for (int i = t; i < NBINS; i += STHREADS) hist[i] = 0;
        __syncthreads();

        // ---- phase 1: load all src/dst (independent loads in flight) ----
        int sk[EPT], dk[EPT];
        if (is64) {
#pragma unroll
            for (int k = 0; k < EPT; ++k) {
                long long e = tbase + (long long)k * STHREADS + t;
                if (e < end) {
                    sk[k] = (int)__builtin_nontemporal_load(&e64[e]);
                    dk[k] = (int)__builtin_nontemporal_load(&e64[E + e]);
                } else { sk[k] = 0; dk[k] = -1; }
            }
        } else {
#pragma unroll
            for (int k = 0; k < EPT; ++k) {
                long long e = tbase + (long long)k * STHREADS + t;
                if (e < end) {
                    sk[k] = __builtin_nontemporal_load(&ei[e]);
                    dk[k] = __builtin_nontemporal_load(&ei[E + e]);
                } else { sk[k] = 0; dk[k] = -1; }
            }
        }

        // ---- phase 2: gather h2 (fp16 table, L2-resident, all in flight) ----
        unsigned int hv[EPT];
#pragma unroll
        for (int k = 0; k < EPT; ++k) hv[k] = (unsigned int)h2f16[sk[k]];

        // ---- phase 3: rank within (tile, bin) ----
        int rk[EPT];
#pragma unroll
        for (int k = 0; k < EPT; ++k)
            if (dk[k] >= 0) rk[k] = atomicAdd(&hist[dk[k] >> BSHIFT], 1);
        __syncthreads();

        // ---- exclusive scan of hist (Hillis-Steele over 256 bins) ----
        if (t < NBINS) scanbuf[t] = hist[t];
        __syncthreads();
        for (int off = 1; off < NBINS; off <<= 1) {
            int v = 0;
            if (t < NBINS && t >= off) v = scanbuf[t - off];
            __syncthreads();
            if (t < NBINS) scanbuf[t] += v;
            __syncthreads();
        }
        if (t < NBINS) toff[t] = scanbuf[t] - hist[t];
        __syncthreads();

        // ---- phase 4: place bin-sorted in LDS ----
#pragma unroll
        for (int k = 0; k < EPT; ++k) {
            if (dk[k] >= 0) {
                int slot = toff[dk[k] >> BSHIFT] + rk[k];
                ents[slot] = ((unsigned int)(dk[k] & DMASK) << 16) | hv[k];
            }
        }
        __syncthreads();

        // ---- phase 5: sequential coalesced copy-out + index row ----
        const int tilecount = scanbuf[NBINS - 1];
        const int g = blockIdx.x * tpb + ti;
        unsigned int* gout = entries + (long long)g * TILE;
        for (int j = t; j < tilecount; j += STHREADS)
            __builtin_nontemporal_store(ents[j], &gout[j]);
        if (t < NBINS)
            __builtin_nontemporal_store(toff[t], &index[(long long)t * ntiles + g]);
        else if (t == NBINS)
            __builtin_nontemporal_store(tilecount, &index[(long long)NBINS * ntiles + g]);
        __syncthreads();
    }
}

// P2: per-bin aggregation. 2 tiles per wave (32-lane halves); LDS sum/cnt.
__global__ void __launch_bounds__(1024)
aggregate_kernel(const unsigned int* __restrict__ entries,
                 const int* __restrict__ index,
                 const float* __restrict__ Wsage,
                 float* __restrict__ out,
                 int n, int ntiles) {
    __shared__ float ssum[4096];
    __shared__ int   scnt[4096];
    const int b = blockIdx.x;
    const int t = threadIdx.x;
    for (int i = t; i < 4096; i += blockDim.x) { ssum[i] = 0.0f; scnt[i] = 0; }
    __syncthreads();

    const int wave = t >> 6;
    const int lane = t & 63;
    const int half = lane >> 5;      // 0 or 1: which tile of the pair
    const int hl   = lane & 31;
    const int* __restrict__ rowS = index + (long long)b * ntiles;
    const int* __restrict__ rowE = index + (long long)(b + 1) * ntiles;

    for (int g = wave * 2 + half; g < ntiles; g += 32) {
        int s = rowS[g];             // broadcast within half-wave
        int e = rowE[g];
        const unsigned int* run = entries + (long long)g * TILE;
        for (int i = s + hl; i < e; i += 32) {
            unsigned int ent = __builtin_nontemporal_load(&run[i]);
            int dlow = (int)(ent >> 16);
            float v  = __half2float(__ushort_as_half((unsigned short)(ent & 0xFFFFu)));
            atomicAdd(&ssum[dlow], v);
            atomicAdd(&scnt[dlow], 1);
        }
    }
    __syncthreads();

    const float w = Wsage[0];
    const int base = b << BSHIFT;
    for (int i = t; i < 4096; i += blockDim.x) {
        int node = base + i;
        if (node < n) {
            float c = (float)scnt[i];
            out[node] = ssum[i] / fmaxf(c, 1.0f) * w;
        }
    }
}

// ---------------- fallback path (R1 packed-atomic) ----------------

#define PACK_SCALE 1048576.0  // 2^20

__global__ void node_f32_kernel(const float* __restrict__ x,
                                const float* __restrict__ W1,
                                const float* __restrict__ b1,
                                const float* __restrict__ W2,
                                const float* __restrict__ b2,
                                float* __restrict__ h2,
                                int n) {
    int i = blockIdx.x * blockDim.x + threadIdx.x;
    if (i >= n) return;
    float xi = x[i];
    float acc = b2[0];
#pragma unroll
    for (int j = 0; j < 4; ++j) {
        float t = fmaxf(W1[j] * xi + b1[j], 0.0f);
        acc += W2[j] * t;
    }
    h2[i] = acc;
}

__global__ void zero_packed_kernel(double* __restrict__ packed, int n) {
    int i = blockIdx.x * blockDim.x + threadIdx.x;
    if (i < n) packed[i] = 0.0;
}

__global__ void edge_atomic_kernel(const int* __restrict__ ei,
                                   const float* __restrict__ h2,
                                   double* __restrict__ packed,
                                   const int* __restrict__ flag,
                                   long long E) {
    long long i      = (long long)blockIdx.x * blockDim.x + threadIdx.x;
    long long stride = (long long)gridDim.x * blockDim.x;
    const int is64 = *flag;
    if (is64) {
        const long long* e64 = (const long long*)ei;
        for (long long e = i; e < E; e += stride) {
            int s = (int)e64[e];
            int d = (int)e64[E + e];
            atomicAdd(&packed[d], (double)h2[s] + PACK_SCALE);
        }
    } else {
        for (long long e = i; e < E; e += stride) {
            int s = ei[e];
            int d = ei[E + e];
            atomicAdd(&packed[d], (double)h2[s] + PACK_SCALE);
        }
    }
}

__global__ void out_packed_kernel(const double* __restrict__ packed,
                                  const float* __restrict__ Wsage,
                                  float* __restrict__ out,
                                  int n) {
    int i = blockIdx.x * blockDim.x + threadIdx.x;
    if (i >= n) return;
    double v   = packed[i];
    double cnt = nearbyint(v * (1.0 / PACK_SCALE));
    double agg = v - cnt * PACK_SCALE;
    out[i] = (float)(agg / fmax(cnt, 1.0)) * Wsage[0];
}

extern "C" void kernel_launch(void* const* d_in, const int* in_sizes, int n_in,
                              void* d_out, int out_size, void* d_ws, size_t ws_size,
                              hipStream_t stream) {
    const float* x     = (const float*)d_in[0];
    const int*   ei    = (const int*)d_in[1];
    const float* W1    = (const float*)d_in[2];
    const float* b1    = (const float*)d_in[3];
    const float* W2    = (const float*)d_in[4];
    const float* b2    = (const float*)d_in[5];
    const float* Wsage = (const float*)d_in[6];

    const int       n = in_sizes[0];                 // 1,000,000
    const long long E = (long long)in_sizes[1] / 2;  // 32,000,000

    const long long chunk  = (E + NBLK - 1) / NBLK;          // 62500
    const int       tpb    = (int)((chunk + TILE - 1) / TILE); // 8
    const int       ntiles = NBLK * tpb;                      // 4096

    // ws layout
    const size_t entries_b = (size_t)ntiles * TILE * 4;
    const size_t index_b   = (size_t)(NBINS + 1) * ntiles * 4;
    const size_t h2_b      = (size_t)n * 2;
    const size_t need      = entries_b + index_b + h2_b + 64;

    if (ws_size >= need) {
        unsigned int*   entries = (unsigned int*)d_ws;
        int*            index   = (int*)((char*)d_ws + entries_b);
        unsigned short* h2f16   = (unsigned short*)((char*)d_ws + entries_b + index_b);
        int*            flag    = (int*)((char*)d_ws + entries_b + index_b + h2_b);

        detect_dtype_kernel<<<1, 64, 0, stream>>>(ei, flag);
        {
            int threads = 256;
            int blocks  = (n + threads - 1) / threads;
            node_kernel<<<blocks, threads, 0, stream>>>(x, W1, b1, W2, b2, h2f16, n);
        }
        scatter_tile_kernel<<<NBLK, STHREADS, 0, stream>>>(ei, h2f16, entries, index,
                                                           flag, E, chunk, tpb, ntiles);
        aggregate_kernel<<<NBINS, 1024, 0, stream>>>(entries, index, Wsage,
                                                     (float*)d_out, n, ntiles);
    } else {
        // fallback: R1 packed-atomic path
        double* packed = (double*)d_ws;
        float*  h2     = (float*)d_out;
        int*    flag   = (int*)(packed + n);

        detect_dtype_kernel<<<1, 64, 0, stream>>>(ei, flag);
        {
            int threads = 256;
            int blocks  = (n + threads - 1) / threads;
            node_f32_kernel<<<blocks, threads, 0, stream>>>(x, W1, b1, W2, b2, h2, n);
            zero_packed_kernel<<<blocks, threads, 0, stream>>>(packed, n);
        }
        edge_atomic_kernel<<<4096, 256, 0, stream>>>(ei, h2, packed, flag, E);
        {
            int threads = 256;
            int blocks  = (n + threads - 1) / threads;
            out_packed_kernel<<<blocks, threads, 0, stream>>>(packed, Wsage,
                                                              (float*)d_out, n);
        }
    }
}

// Round 7
// 314.411 us; speedup vs baseline: 9.7818x; 1.2760x over previous
//
#include <hip/hip_runtime.h>
#include <hip/hip_fp16.h>

// N=1e6 nodes, E=32e6 edges.
// out[i] = (sum_{e: dst=i} h2[src_e]) / max(deg_in(i),1) * Wsage
// h2[v] = sum_j W2[j]*relu(W1[j]*x[v]+b1[j]) + b2
//
// R6 (on top of R5's one-pass tile-sorted scatter):
//  - aggregate was LDS-atomic bound (207us for 131MB, 8% HBM, 2 LDS atomics
//    per entry, 1 block/CU). Now: ONE packed f64 LDS atomic per entry
//    (acc += v + 2^20; native ds_add_f64), and 2 blocks per bin (grid 512,
//    each block owns half the tiles) -> 32 waves/CU. Blocks write packed
//    partials to global; finalize kernel merges+decodes -> out.
//
// ws layout: entries uint[NTILES*TILE]; index int[257*NTILES];
//            partial double[2*NBINS*4096]; h2f16 ushort[n]; flag int.
// Fallback (ws too small): R1 packed f64-atomic path.

#define NBINS    256
#define BSHIFT   12
#define DMASK    4095
#define NBLK     512
#define STHREADS 512
#define EPT      16
#define TILE     (STHREADS * EPT)   // 8192
#define PACK_SCALE 1048576.0        // 2^20

// ---- dtype probe: int64 edge_index => every odd 32-bit word is 0 ----
__global__ void detect_dtype_kernel(const int* __restrict__ ei, int* __restrict__ flag) {
    if (threadIdx.x == 0 && blockIdx.x == 0) {
        int is64 = 1;
        for (int i = 1; i < 256; i += 2) {
            if (ei[i] != 0) { is64 = 0; break; }
        }
        *flag = is64;
    }
}

__global__ void node_kernel(const float* __restrict__ x,
                            const float* __restrict__ W1,
                            const float* __restrict__ b1,
                            const float* __restrict__ W2,
                            const float* __restrict__ b2,
                            unsigned short* __restrict__ h2f16,
                            int n) {
    int i = blockIdx.x * blockDim.x + threadIdx.x;
    if (i >= n) return;
    float xi = x[i];
    float acc = b2[0];
#pragma unroll
    for (int j = 0; j < 4; ++j) {
        float t = fmaxf(W1[j] * xi + b1[j], 0.0f);
        acc += W2[j] * t;
    }
    h2f16[i] = __half_as_ushort(__float2half(acc));
}

// P1: one-pass tile-sorted scatter into block-private slots + bin-major index.
__global__ void __launch_bounds__(STHREADS)
scatter_tile_kernel(const int* __restrict__ ei,
                    const unsigned short* __restrict__ h2f16,
                    unsigned int* __restrict__ entries,
                    int* __restrict__ index,   // [257][ntiles]
                    const int* __restrict__ flag,
                    long long E, long long chunk, int tpb, int ntiles) {
    __shared__ unsigned int ents[TILE];
    __shared__ int hist[NBINS];
    __shared__ int scanbuf[NBINS];
    __shared__ int toff[NBINS];

    const int t = threadIdx.x;
    long long start = (long long)blockIdx.x * chunk;
    long long end   = start + chunk; if (end > E) end = E;
    const int is64 = *flag;
    const long long* e64 = (const long long*)ei;

    int ti = 0;
    for (long long tbase = start; tbase < end; tbase += TILE, ++ti) {
        for (int i = t; i < NBINS; i += STHREADS) hist[i] = 0;
        __syncthreads();

        // ---- phase 1: load all src/dst (independent loads in flight) ----
        int sk[EPT], dk[EPT];
        if (is64) {
#pragma unroll
            for (int k = 0; k < EPT; ++k) {
                long long e = tbase + (long long)k * STHREADS + t;
                if (e < end) {
                    sk[k] = (int)__builtin_nontemporal_load(&e64[e]);
                    dk[k] = (int)__builtin_nontemporal_load(&e64[E + e]);
                } else { sk[k] = 0; dk[k] = -1; }
            }
        } else {
#pragma unroll
            for (int k = 0; k < EPT; ++k) {
                long long e = tbase + (long long)k * STHREADS + t;
                if (e < end) {
                    sk[k] = __builtin_nontemporal_load(&ei[e]);
                    dk[k] = __builtin_nontemporal_load(&ei[E + e]);
                } else { sk[k] = 0; dk[k] = -1; }
            }
        }

        // ---- phase 2: gather h2 (fp16 table, L2-resident, all in flight) ----
        unsigned int hv[EPT];
#pragma unroll
        for (int k = 0; k < EPT; ++k) hv[k] = (unsigned int)h2f16[sk[k]];

        // ---- phase 3: rank within (tile, bin) ----
        int rk[EPT];
#pragma unroll
        for (int k = 0; k < EPT; ++k)
            if (dk[k] >= 0) rk[k] = atomicAdd(&hist[dk[k] >> BSHIFT], 1);
        __syncthreads();

        // ---- exclusive scan of hist (Hillis-Steele over 256 bins) ----
        if (t < NBINS) scanbuf[t] = hist[t];
        __syncthreads();
        for (int off = 1; off < NBINS; off <<= 1) {
            int v = 0;
            if (t < NBINS && t >= off) v = scanbuf[t - off];
            __syncthreads();
            if (t < NBINS) scanbuf[t] += v;
            __syncthreads();
        }
        if (t < NBINS) toff[t] = scanbuf[t] - hist[t];
        __syncthreads();

        // ---- phase 4: place bin-sorted in LDS ----
#pragma unroll
        for (int k = 0; k < EPT; ++k) {
            if (dk[k] >= 0) {
                int slot = toff[dk[k] >> BSHIFT] + rk[k];
                ents[slot] = ((unsigned int)(dk[k] & DMASK) << 16) | hv[k];
            }
        }
        __syncthreads();

        // ---- phase 5: sequential coalesced copy-out + index row ----
        const int tilecount = scanbuf[NBINS - 1];
        const int g = blockIdx.x * tpb + ti;
        unsigned int* gout = entries + (long long)g * TILE;
        for (int j = t; j < tilecount; j += STHREADS)
            __builtin_nontemporal_store(ents[j], &gout[j]);
        if (t < NBINS)
            __builtin_nontemporal_store(toff[t], &index[(long long)t * ntiles + g]);
        else if (t == NBINS)
            __builtin_nontemporal_store(tilecount, &index[(long long)NBINS * ntiles + g]);
        __syncthreads();
    }
}

// P2: per-(bin,half) aggregation with ONE packed f64 LDS atomic per entry.
// grid = NBINS*2; block (bin = blockIdx.x>>1, sub = blockIdx.x&1).
__global__ void __launch_bounds__(1024, 8)
aggregate_kernel(const unsigned int* __restrict__ entries,
                 const int* __restrict__ index,
                 double* __restrict__ partial,   // [2*NBINS][4096]
                 int ntiles) {
    __shared__ double acc[4096];
    const int b   = blockIdx.x >> 1;
    const int sub = blockIdx.x & 1;
    const int t   = threadIdx.x;
    for (int i = t; i < 4096; i += blockDim.x) acc[i] = 0.0;
    __syncthreads();

    const int half_t = ntiles >> 1;
    const int gbase  = sub * half_t;
    const int wave = t >> 6;
    const int lane = t & 63;
    const int half = lane >> 5;      // 0 or 1: which tile of the pair
    const int hl   = lane & 31;
    const int* __restrict__ rowS = index + (long long)b * ntiles;
    const int* __restrict__ rowE = index + (long long)(b + 1) * ntiles;

    for (int g = gbase + wave * 2 + half; g < gbase + half_t; g += 32) {
        int s = rowS[g];             // broadcast within half-wave
        int e = rowE[g];
        const unsigned int* run = entries + (long long)g * TILE;
        for (int i = s + hl; i < e; i += 32) {
            unsigned int ent = __builtin_nontemporal_load(&run[i]);
            int dlow = (int)(ent >> 16);
            float v  = __half2float(__ushort_as_half((unsigned short)(ent & 0xFFFFu)));
            atomicAdd(&acc[dlow], (double)v + PACK_SCALE);  // ds_add_f64
        }
    }
    __syncthreads();

    double* p = partial + (long long)blockIdx.x * 4096;
    for (int i = t; i < 4096; i += blockDim.x)
        __builtin_nontemporal_store(acc[i], &p[i]);
}

// P3: finalize — merge 2 partials per node, decode, write out.
__global__ void finalize_kernel(const double* __restrict__ partial,
                                const float* __restrict__ Wsage,
                                float* __restrict__ out,
                                int n) {
    int i = blockIdx.x * blockDim.x + threadIdx.x;
    if (i >= n) return;
    int b    = i >> BSHIFT;
    int dlow = i & DMASK;
    double v = partial[(long long)(b * 2) * 4096 + dlow]
             + partial[(long long)(b * 2 + 1) * 4096 + dlow];
    double cnt = nearbyint(v * (1.0 / PACK_SCALE));
    double agg = v - cnt * PACK_SCALE;
    out[i] = (float)(agg / fmax(cnt, 1.0)) * Wsage[0];
}

// ---------------- fallback path (R1 packed-atomic) ----------------

__global__ void node_f32_kernel(const float* __restrict__ x,
                                const float* __restrict__ W1,
                                const float* __restrict__ b1,
                                const float* __restrict__ W2,
                                const float* __restrict__ b2,
                                float* __restrict__ h2,
                                int n) {
    int i = blockIdx.x * blockDim.x + threadIdx.x;
    if (i >= n) return;
    float xi = x[i];
    float acc = b2[0];
#pragma unroll
    for (int j = 0; j < 4; ++j) {
        float t = fmaxf(W1[j] * xi + b1[j], 0.0f);
        acc += W2[j] * t;
    }
    h2[i] = acc;
}

__global__ void zero_packed_kernel(double* __restrict__ packed, int n) {
    int i = blockIdx.x * blockDim.x + threadIdx.x;
    if (i < n) packed[i] = 0.0;
}

__global__ void edge_atomic_kernel(const int* __restrict__ ei,
                                   const float* __restrict__ h2,
                                   double* __restrict__ packed,
                                   const int* __restrict__ flag,
                                   long long E) {
    long long i      = (long long)blockIdx.x * blockDim.x + threadIdx.x;
    long long stride = (long long)gridDim.x * blockDim.x;
    const int is64 = *flag;
    if (is64) {
        const long long* e64 = (const long long*)ei;
        for (long long e = i; e < E; e += stride) {
            int s = (int)e64[e];
            int d = (int)e64[E + e];
            atomicAdd(&packed[d], (double)h2[s] + PACK_SCALE);
        }
    } else {
        for (long long e = i; e < E; e += stride) {
            int s = ei[e];
            int d = ei[E + e];
            atomicAdd(&packed[d], (double)h2[s] + PACK_SCALE);
        }
    }
}

__global__ void out_packed_kernel(const double* __restrict__ packed,
                                  const float* __restrict__ Wsage,
                                  float* __restrict__ out,
                                  int n) {
    int i = blockIdx.x * blockDim.x + threadIdx.x;
    if (i >= n) return;
    double v   = packed[i];
    double cnt = nearbyint(v * (1.0 / PACK_SCALE));
    double agg = v - cnt * PACK_SCALE;
    out[i] = (float)(agg / fmax(cnt, 1.0)) * Wsage[0];
}

extern "C" void kernel_launch(void* const* d_in, const int* in_sizes, int n_in,
                              void* d_out, int out_size, void* d_ws, size_t ws_size,
                              hipStream_t stream) {
    const float* x     = (const float*)d_in[0];
    const int*   ei    = (const int*)d_in[1];
    const float* W1    = (const float*)d_in[2];
    const float* b1    = (const float*)d_in[3];
    const float* W2    = (const float*)d_in[4];
    const float* b2    = (const float*)d_in[5];
    const float* Wsage = (const float*)d_in[6];

    const int       n = in_sizes[0];                 // 1,000,000
    const long long E = (long long)in_sizes[1] / 2;  // 32,000,000

    const long long chunk  = (E + NBLK - 1) / NBLK;            // 62500
    const int       tpb    = (int)((chunk + TILE - 1) / TILE); // 8
    const int       ntiles = NBLK * tpb;                       // 4096

    // ws layout
    const size_t entries_b = (size_t)ntiles * TILE * 4;
    const size_t index_b   = (size_t)(NBINS + 1) * ntiles * 4;
    const size_t partial_b = (size_t)2 * NBINS * 4096 * 8;
    const size_t h2_b      = (size_t)n * 2;
    const size_t need      = entries_b + index_b + partial_b + h2_b + 64;

    if (ws_size >= need) {
        unsigned int*   entries = (unsigned int*)d_ws;
        int*            index   = (int*)((char*)d_ws + entries_b);
        double*         partial = (double*)((char*)d_ws + entries_b + index_b);
        unsigned short* h2f16   = (unsigned short*)((char*)d_ws + entries_b + index_b + partial_b);
        int*            flag    = (int*)((char*)d_ws + entries_b + index_b + partial_b + h2_b);

        detect_dtype_kernel<<<1, 64, 0, stream>>>(ei, flag);
        {
            int threads = 256;
            int blocks  = (n + threads - 1) / threads;
            node_kernel<<<blocks, threads, 0, stream>>>(x, W1, b1, W2, b2, h2f16, n);
        }
        scatter_tile_kernel<<<NBLK, STHREADS, 0, stream>>>(ei, h2f16, entries, index,
                                                           flag, E, chunk, tpb, ntiles);
        aggregate_kernel<<<NBINS * 2, 1024, 0, stream>>>(entries, index, partial, ntiles);
        {
            int threads = 256;
            int blocks  = (n + threads - 1) / threads;
            finalize_kernel<<<blocks, threads, 0, stream>>>(partial, Wsage,
                                                            (float*)d_out, n);
        }
    } else {
        // fallback: R1 packed-atomic path
        double* packed = (double*)d_ws;
        float*  h2     = (float*)d_out;
        int*    flag   = (int*)(packed + n);

        detect_dtype_kernel<<<1, 64, 0, stream>>>(ei, flag);
        {
            int threads = 256;
            int blocks  = (n + threads - 1) / threads;
            node_f32_kernel<<<blocks, threads, 0, stream>>>(x, W1, b1, W2, b2, h2, n);
            zero_packed_kernel<<<blocks, threads, 0, stream>>>(packed, n);
        }
        edge_atomic_kernel<<<4096, 256, 0, stream>>>(ei, h2, packed, flag, E);
        {
            int threads = 256;
            int blocks  = (n + threads - 1) / threads;
            out_packed_kernel<<<blocks, threads, 0, stream>>>(packed, Wsage,
                                                              (float*)d_out, n);
        }
    }
}

// Round 8
// 310.756 us; speedup vs baseline: 9.8968x; 1.0118x over previous
//
#include <hip/hip_runtime.h>
#include <hip/hip_fp16.h>

// N=1e6 nodes, E=32e6 edges.
// out[i] = (sum_{e: dst=i} h2[src_e]) / max(deg_in(i),1) * Wsage
// h2[v] = sum_j W2[j]*relu(W1[j]*x[v]+b1[j]) + b2
//
// R7 (on R6): scatter was latency-bound at 40% occupancy (2 blocks/CU,
// grid=512) with 16 barriers/tile in the Hillis-Steele scan.
//  - NBLK 1024 -> 4 blocks/CU (143KB LDS), 32 waves/CU.
//  - single-wave __shfl_up scan (1 barrier) replaces Hillis-Steele (16).
//  - ntiles stays 4096 (tpb drops 8->4); aggregate/finalize unchanged.
//
// ws layout: entries uint[NTILES*TILE]; index int[257*NTILES];
//            partial double[2*NBINS*4096]; h2f16 ushort[n]; flag int.
// Fallback (ws too small): R1 packed f64-atomic path.

#define NBINS    256
#define BSHIFT   12
#define DMASK    4095
#define NBLK     1024
#define STHREADS 512
#define EPT      16
#define TILE     (STHREADS * EPT)   // 8192
#define PACK_SCALE 1048576.0        // 2^20

// ---- dtype probe: int64 edge_index => every odd 32-bit word is 0 ----
__global__ void detect_dtype_kernel(const int* __restrict__ ei, int* __restrict__ flag) {
    if (threadIdx.x == 0 && blockIdx.x == 0) {
        int is64 = 1;
        for (int i = 1; i < 256; i += 2) {
            if (ei[i] != 0) { is64 = 0; break; }
        }
        *flag = is64;
    }
}

__global__ void node_kernel(const float* __restrict__ x,
                            const float* __restrict__ W1,
                            const float* __restrict__ b1,
                            const float* __restrict__ W2,
                            const float* __restrict__ b2,
                            unsigned short* __restrict__ h2f16,
                            int n) {
    int i = blockIdx.x * blockDim.x + threadIdx.x;
    if (i >= n) return;
    float xi = x[i];
    float acc = b2[0];
#pragma unroll
    for (int j = 0; j < 4; ++j) {
        float t = fmaxf(W1[j] * xi + b1[j], 0.0f);
        acc += W2[j] * t;
    }
    h2f16[i] = __half_as_ushort(__float2half(acc));
}

// P1: one-pass tile-sorted scatter into block-private slots + bin-major index.
__global__ void __launch_bounds__(STHREADS)
scatter_tile_kernel(const int* __restrict__ ei,
                    const unsigned short* __restrict__ h2f16,
                    unsigned int* __restrict__ entries,
                    int* __restrict__ index,   // [257][ntiles]
                    const int* __restrict__ flag,
                    long long E, long long chunk, int tpb, int ntiles) {
    __shared__ unsigned int ents[TILE];
    __shared__ int hist[NBINS];
    __shared__ int toff[NBINS];
    __shared__ int s_total;

    const int t = threadIdx.x;
    long long start = (long long)blockIdx.x * chunk;
    long long end   = start + chunk; if (end > E) end = E;
    const int is64 = *flag;
    const long long* e64 = (const long long*)ei;

    int ti = 0;
    for (long long tbase = start; tbase < end; tbase += TILE, ++ti) {
        for (int i = t; i < NBINS; i += STHREADS) hist[i] = 0;
        __syncthreads();

        // ---- phase 1: load all src/dst (independent loads in flight) ----
        int sk[EPT], dk[EPT];
        if (is64) {
#pragma unroll
            for (int k = 0; k < EPT; ++k) {
                long long e = tbase + (long long)k * STHREADS + t;
                if (e < end) {
                    sk[k] = (int)__builtin_nontemporal_load(&e64[e]);
                    dk[k] = (int)__builtin_nontemporal_load(&e64[E + e]);
                } else { sk[k] = 0; dk[k] = -1; }
            }
        } else {
#pragma unroll
            for (int k = 0; k < EPT; ++k) {
                long long e = tbase + (long long)k * STHREADS + t;
                if (e < end) {
                    sk[k] = __builtin_nontemporal_load(&ei[e]);
                    dk[k] = __builtin_nontemporal_load(&ei[E + e]);
                } else { sk[k] = 0; dk[k] = -1; }
            }
        }

        // ---- phase 2: gather h2 (fp16 table, L2-resident, all in flight) ----
        unsigned int hv[EPT];
#pragma unroll
        for (int k = 0; k < EPT; ++k) hv[k] = (unsigned int)h2f16[sk[k]];

        // ---- phase 3: rank within (tile, bin) ----
        int rk[EPT];
#pragma unroll
        for (int k = 0; k < EPT; ++k)
            if (dk[k] >= 0) rk[k] = atomicAdd(&hist[dk[k] >> BSHIFT], 1);
        __syncthreads();

        // ---- exclusive scan over 256 bins: wave 0 only, shfl scan ----
        if (t < 64) {
            const int base = t * 4;
            int a0 = hist[base], a1 = hist[base + 1],
                a2 = hist[base + 2], a3 = hist[base + 3];
            int s  = a0 + a1 + a2 + a3;
            int sc = s;
#pragma unroll
            for (int off = 1; off < 64; off <<= 1) {
                int up = __shfl_up(sc, off, 64);
                if (t >= off) sc += up;
            }
            int excl = sc - s;
            toff[base]     = excl;
            toff[base + 1] = excl + a0;
            toff[base + 2] = excl + a0 + a1;
            toff[base + 3] = excl + a0 + a1 + a2;
            if (t == 63) s_total = sc;
        }
        __syncthreads();

        // ---- phase 4: place bin-sorted in LDS ----
#pragma unroll
        for (int k = 0; k < EPT; ++k) {
            if (dk[k] >= 0) {
                int slot = toff[dk[k] >> BSHIFT] + rk[k];
                ents[slot] = ((unsigned int)(dk[k] & DMASK) << 16) | hv[k];
            }
        }
        __syncthreads();

        // ---- phase 5: sequential coalesced copy-out + index row ----
        const int tilecount = s_total;
        const int g = blockIdx.x * tpb + ti;
        unsigned int* gout = entries + (long long)g * TILE;
        for (int j = t; j < tilecount; j += STHREADS)
            __builtin_nontemporal_store(ents[j], &gout[j]);
        if (t < NBINS)
            __builtin_nontemporal_store(toff[t], &index[(long long)t * ntiles + g]);
        else if (t == NBINS)
            __builtin_nontemporal_store(tilecount, &index[(long long)NBINS * ntiles + g]);
        __syncthreads();
    }
}

// P2: per-(bin,half) aggregation with ONE packed f64 LDS atomic per entry.
// grid = NBINS*2; block (bin = blockIdx.x>>1, sub = blockIdx.x&1).
__global__ void __launch_bounds__(1024, 8)
aggregate_kernel(const unsigned int* __restrict__ entries,
                 const int* __restrict__ index,
                 double* __restrict__ partial,   // [2*NBINS][4096]
                 int ntiles) {
    __shared__ double acc[4096];
    const int b   = blockIdx.x >> 1;
    const int sub = blockIdx.x & 1;
    const int t   = threadIdx.x;
    for (int i = t; i < 4096; i += blockDim.x) acc[i] = 0.0;
    __syncthreads();

    const int half_t = ntiles >> 1;
    const int gbase  = sub * half_t;
    const int wave = t >> 6;
    const int lane = t & 63;
    const int half = lane >> 5;      // 0 or 1: which tile of the pair
    const int hl   = lane & 31;
    const int* __restrict__ rowS = index + (long long)b * ntiles;
    const int* __restrict__ rowE = index + (long long)(b + 1) * ntiles;

    for (int g = gbase + wave * 2 + half; g < gbase + half_t; g += 32) {
        int s = rowS[g];             // broadcast within half-wave
        int e = rowE[g];
        const unsigned int* run = entries + (long long)g * TILE;
        for (int i = s + hl; i < e; i += 32) {
            unsigned int ent = __builtin_nontemporal_load(&run[i]);
            int dlow = (int)(ent >> 16);
            float v  = __half2float(__ushort_as_half((unsigned short)(ent & 0xFFFFu)));
            atomicAdd(&acc[dlow], (double)v + PACK_SCALE);  // ds_add_f64
        }
    }
    __syncthreads();

    double* p = partial + (long long)blockIdx.x * 4096;
    for (int i = t; i < 4096; i += blockDim.x)
        __builtin_nontemporal_store(acc[i], &p[i]);
}

// P3: finalize — merge 2 partials per node, decode, write out.
__global__ void finalize_kernel(const double* __restrict__ partial,
                                const float* __restrict__ Wsage,
                                float* __restrict__ out,
                                int n) {
    int i = blockIdx.x * blockDim.x + threadIdx.x;
    if (i >= n) return;
    int b    = i >> BSHIFT;
    int dlow = i & DMASK;
    double v = partial[(long long)(b * 2) * 4096 + dlow]
             + partial[(long long)(b * 2 + 1) * 4096 + dlow];
    double cnt = nearbyint(v * (1.0 / PACK_SCALE));
    double agg = v - cnt * PACK_SCALE;
    out[i] = (float)(agg / fmax(cnt, 1.0)) * Wsage[0];
}

// ---------------- fallback path (R1 packed-atomic) ----------------

__global__ void node_f32_kernel(const float* __restrict__ x,
                                const float* __restrict__ W1,
                                const float* __restrict__ b1,
                                const float* __restrict__ W2,
                                const float* __restrict__ b2,
                                float* __restrict__ h2,
                                int n) {
    int i = blockIdx.x * blockDim.x + threadIdx.x;
    if (i >= n) return;
    float xi = x[i];
    float acc = b2[0];
#pragma unroll
    for (int j = 0; j < 4; ++j) {
        float t = fmaxf(W1[j] * xi + b1[j], 0.0f);
        acc += W2[j] * t;
    }
    h2[i] = acc;
}

__global__ void zero_packed_kernel(double* __restrict__ packed, int n) {
    int i = blockIdx.x * blockDim.x + threadIdx.x;
    if (i < n) packed[i] = 0.0;
}

__global__ void edge_atomic_kernel(const int* __restrict__ ei,
                                   const float* __restrict__ h2,
                                   double* __restrict__ packed,
                                   const int* __restrict__ flag,
                                   long long E) {
    long long i      = (long long)blockIdx.x * blockDim.x + threadIdx.x;
    long long stride = (long long)gridDim.x * blockDim.x;
    const int is64 = *flag;
    if (is64) {
        const long long* e64 = (const long long*)ei;
        for (long long e = i; e < E; e += stride) {
            int s = (int)e64[e];
            int d = (int)e64[E + e];
            atomicAdd(&packed[d], (double)h2[s] + PACK_SCALE);
        }
    } else {
        for (long long e = i; e < E; e += stride) {
            int s = ei[e];
            int d = ei[E + e];
            atomicAdd(&packed[d], (double)h2[s] + PACK_SCALE);
        }
    }
}

__global__ void out_packed_kernel(const double* __restrict__ packed,
                                  const float* __restrict__ Wsage,
                                  float* __restrict__ out,
                                  int n) {
    int i = blockIdx.x * blockDim.x + threadIdx.x;
    if (i >= n) return;
    double v   = packed[i];
    double cnt = nearbyint(v * (1.0 / PACK_SCALE));
    double agg = v - cnt * PACK_SCALE;
    out[i] = (float)(agg / fmax(cnt, 1.0)) * Wsage[0];
}

extern "C" void kernel_launch(void* const* d_in, const int* in_sizes, int n_in,
                              void* d_out, int out_size, void* d_ws, size_t ws_size,
                              hipStream_t stream) {
    const float* x     = (const float*)d_in[0];
    const int*   ei    = (const int*)d_in[1];
    const float* W1    = (const float*)d_in[2];
    const float* b1    = (const float*)d_in[3];
    const float* W2    = (const float*)d_in[4];
    const float* b2    = (const float*)d_in[5];
    const float* Wsage = (const float*)d_in[6];

    const int       n = in_sizes[0];                 // 1,000,000
    const long long E = (long long)in_sizes[1] / 2;  // 32,000,000

    const long long chunk  = (E + NBLK - 1) / NBLK;            // 31250
    const int       tpb    = (int)((chunk + TILE - 1) / TILE); // 4
    const int       ntiles = NBLK * tpb;                       // 4096

    // ws layout
    const size_t entries_b = (size_t)ntiles * TILE * 4;
    const size_t index_b   = (size_t)(NBINS + 1) * ntiles * 4;
    const size_t partial_b = (size_t)2 * NBINS * 4096 * 8;
    const size_t h2_b      = (size_t)n * 2;
    const size_t need      = entries_b + index_b + partial_b + h2_b + 64;

    if (ws_size >= need) {
        unsigned int*   entries = (unsigned int*)d_ws;
        int*            index   = (int*)((char*)d_ws + entries_b);
        double*         partial = (double*)((char*)d_ws + entries_b + index_b);
        unsigned short* h2f16   = (unsigned short*)((char*)d_ws + entries_b + index_b + partial_b);
        int*            flag    = (int*)((char*)d_ws + entries_b + index_b + partial_b + h2_b);

        detect_dtype_kernel<<<1, 64, 0, stream>>>(ei, flag);
        {
            int threads = 256;
            int blocks  = (n + threads - 1) / threads;
            node_kernel<<<blocks, threads, 0, stream>>>(x, W1, b1, W2, b2, h2f16, n);
        }
        scatter_tile_kernel<<<NBLK, STHREADS, 0, stream>>>(ei, h2f16, entries, index,
                                                           flag, E, chunk, tpb, ntiles);
        aggregate_kernel<<<NBINS * 2, 1024, 0, stream>>>(entries, index, partial, ntiles);
        {
            int threads = 256;
            int blocks  = (n + threads - 1) / threads;
            finalize_kernel<<<blocks, threads, 0, stream>>>(partial, Wsage,
                                                            (float*)d_out, n);
        }
    } else {
        // fallback: R1 packed-atomic path
        double* packed = (double*)d_ws;
        float*  h2     = (float*)d_out;
        int*    flag   = (int*)(packed + n);

        detect_dtype_kernel<<<1, 64, 0, stream>>>(ei, flag);
        {
            int threads = 256;
            int blocks  = (n + threads - 1) / threads;
            node_f32_kernel<<<blocks, threads, 0, stream>>>(x, W1, b1, W2, b2, h2, n);
            zero_packed_kernel<<<blocks, threads, 0, stream>>>(packed, n);
        }
        edge_atomic_kernel<<<4096, 256, 0, stream>>>(ei, h2, packed, flag, E);
        {
            int threads = 256;
            int blocks  = (n + threads - 1) / threads;
            out_packed_kernel<<<blocks, threads, 0, stream>>>(packed, Wsage,
                                                              (float*)d_out, n);
        }
    }
}